// Round 4
// baseline (194.640 us; speedup 1.0000x reference)
//
#include <hip/hip_runtime.h>

#define NPG 127
#define EPG 2032
#define NGRAPH 4096
#define NE (EPG * NGRAPH)
#define F1 16
#define F2 28

// arena layout (float indices)
#define EPK  0       // 2032 ints: packed edges (dead after CSR scatter)
#define A2   0       // 2032 floats: aggregated layer-2 input, 127x16 plain   (reuses EPK)
#define XS   2032    // 508  floats: dinv-scaled x, 127x4 (slot 3 = pad)
#define HS2  2540    // 2032 floats: layer-2 gather source, 127x16 slot-rotated
#define H2   4572    // 3556 floats: final node features 127x28 plain
#define XRAW 4572    // 381  floats: raw x staging (dead before H2 written)
#define ARENA 8128

__global__ __launch_bounds__(256, 4) void gcn_fused(
    const float* __restrict__ x, const int* __restrict__ ei,
    const float* __restrict__ W1, const float* __restrict__ b1,
    const float* __restrict__ W2, const float* __restrict__ b2,
    const float* __restrict__ lw1, const float* __restrict__ lb1,
    const float* __restrict__ lw2, const float* __restrict__ lb2,
    float* __restrict__ out)
{
    __shared__ __align__(16) float arena[ARENA];
    __shared__ unsigned short csr[EPG];     // incoming-edge src ids grouped by dst
    __shared__ int starts[NPG + 1];
    __shared__ int cursor[NPG];
    __shared__ float dinv[NPG];
    __shared__ float w1s[48], b1s[F1], w2s[F1 * F2], b2s[F2];
    __shared__ float lb1s[16], lw2s[32], lb2s[2];
    __shared__ float wsum[64];              // 4 waves x 16 head partials
    __shared__ float gsh[16];
    __shared__ int is64;

    const int t = threadIdx.x;
    const int g = blockIdx.x;
    const int nodebase = g * NPG;
    const int ebase = g * EPG;

    // ---- dtype probe: int64 edge_index has all-zero hi-words (ids < 2^31) ----
    if (t < 64) {
        int w = ei[2 * t + 1];
        unsigned long long m = __ballot(w != 0);
        if (t == 0) is64 = (m == 0ULL) ? 1 : 0;
    }
    // ---- init + small weights ----
    if (t < NPG + 1) starts[t] = 0;
    if (t < 48)       w1s[t]        = W1[t];
    else if (t < 64)  b1s[t - 48]   = b1[t - 48];
    else if (t < 92)  b2s[t - 64]   = b2[t - 64];
    else if (t < 108) lb1s[t - 92]  = lb1[t - 92];
    else if (t < 140) lw2s[t - 108] = lw2[t - 108];
    else if (t < 142) lb2s[t - 140] = lb2[t - 140];
    for (int i = t; i < F1 * F2; i += 256) w2s[i] = W2[i];
    __syncthreads();

    // ---- load edges (vectorized): pack (src,dst), count in-degree; stage raw x ----
    int* epk = (int*)&arena[EPK];
    if (is64) {
        const long long* ei64 = (const long long*)ei;
        const longlong2* s2 = (const longlong2*)(ei64 + ebase);
        const longlong2* d2 = (const longlong2*)(ei64 + NE + ebase);
        for (int q = t; q < EPG / 2; q += 256) {
            longlong2 ss = s2[q], dd = d2[q];
            int s0 = (int)ss.x - nodebase, d0 = (int)dd.x - nodebase;
            int s1 = (int)ss.y - nodebase, d1 = (int)dd.y - nodebase;
            epk[2 * q + 0] = (s0 << 8) | d0;  atomicAdd(&starts[d0 + 1], 1);
            epk[2 * q + 1] = (s1 << 8) | d1;  atomicAdd(&starts[d1 + 1], 1);
        }
    } else {
        const int4* s4 = (const int4*)(ei + ebase);
        const int4* d4 = (const int4*)(ei + NE + ebase);
        for (int q = t; q < EPG / 4; q += 256) {
            int4 ss = s4[q], dd = d4[q];
            int e0 = 4 * q;
            epk[e0 + 0] = ((ss.x - nodebase) << 8) | (dd.x - nodebase);
            epk[e0 + 1] = ((ss.y - nodebase) << 8) | (dd.y - nodebase);
            epk[e0 + 2] = ((ss.z - nodebase) << 8) | (dd.z - nodebase);
            epk[e0 + 3] = ((ss.w - nodebase) << 8) | (dd.w - nodebase);
            atomicAdd(&starts[(dd.x - nodebase) + 1], 1);
            atomicAdd(&starts[(dd.y - nodebase) + 1], 1);
            atomicAdd(&starts[(dd.z - nodebase) + 1], 1);
            atomicAdd(&starts[(dd.w - nodebase) + 1], 1);
        }
    }
    for (int i = t; i < NPG * 3; i += 256) arena[XRAW + i] = x[nodebase * 3 + i];
    __syncthreads();
    if (t < NPG) dinv[t] = rsqrtf((float)(starts[t + 1] + 1));  // +1 self-loop
    __syncthreads();
    // ---- Hillis-Steele scan -> exclusive CSR offsets ----
    #pragma unroll
    for (int off = 1; off < 128; off <<= 1) {
        int v = 0;
        if (t < 128) { v = starts[t]; if (t >= off) v += starts[t - off]; }
        __syncthreads();
        if (t < 128) starts[t] = v;
        __syncthreads();
    }
    // cursor init + pre-scaled x rows (dinv known)
    if (t < NPG) {
        cursor[t] = starts[t];
        float di = dinv[t];
        float4 xr;
        xr.x = arena[XRAW + t * 3 + 0] * di;
        xr.y = arena[XRAW + t * 3 + 1] * di;
        xr.z = arena[XRAW + t * 3 + 2] * di;
        xr.w = 0.f;
        *(float4*)&arena[XS + t * 4] = xr;
    }
    __syncthreads();
    // ---- scatter into CSR ----
    for (int e = t; e < EPG; e += 256) {
        int pk = epk[e];
        int d = pk & 255, s = pk >> 8;
        int pos = atomicAdd(&cursor[d], 1);
        csr[pos] = (unsigned short)s;
    }
    __syncthreads();

    // ---- layer 1: aggregate 3-dim x, then h1 = relu(agg . W1 + b1) * dinv ----
    // pair (i, half): register accumulate over split edge list, shfl merge
    if (t < 2 * NPG) {
        const int i = t >> 1, half = t & 1;
        const int e0 = starts[i], e1 = starts[i + 1];
        float ax = 0.f, ay = 0.f, az = 0.f;
        for (int k = e0 + half; k < e1; k += 2) {
            int s = csr[k];
            const float4 v = *(const float4*)&arena[XS + s * 4];
            ax += v.x; ay += v.y; az += v.z;
        }
        if (!half) {  // self-loop once
            const float4 v = *(const float4*)&arena[XS + i * 4];
            ax += v.x; ay += v.y; az += v.z;
        }
        ax += __shfl_xor(ax, 1);
        ay += __shfl_xor(ay, 1);
        az += __shfl_xor(az, 1);
        const float di = dinv[i];
        ax *= di; ay *= di; az *= di;
        // each lane computes 8 of 16 features; write 2 rotated float4 slots
        const int fb = half * 8;
        float h[8];
        #pragma unroll
        for (int f = 0; f < 8; ++f) {
            float v = ax * w1s[fb + f] + ay * w1s[16 + fb + f] + az * w1s[32 + fb + f];
            h[f] = fmaxf(v + b1s[fb + f], 0.f) * di;   // pre-scale for layer-2 gather
        }
        const int rot = (i >> 1) & 3;
        const int s0 = ((half * 2 + 0) + rot) & 3;
        const int s1 = ((half * 2 + 1) + rot) & 3;
        *(float4*)&arena[HS2 + i * 16 + s0 * 4] = make_float4(h[0], h[1], h[2], h[3]);
        *(float4*)&arena[HS2 + i * 16 + s1 * 4] = make_float4(h[4], h[5], h[6], h[7]);
    }
    __syncthreads();

    // ---- layer 2 aggregate: 16-dim gather into registers, write A2 (plain) ----
    if (t < 2 * NPG) {
        const int i = t >> 1, half = t & 1;
        const int e0 = starts[i], e1 = starts[i + 1];
        float4 c0 = {0,0,0,0}, c1 = {0,0,0,0}, c2 = {0,0,0,0}, c3 = {0,0,0,0};
        for (int k = e0 + half; k < e1; k += 2) {
            int s = csr[k];
            const int b = HS2 + s * 16;
            const int r = (s >> 1) & 3;
            const float4 v0 = *(const float4*)&arena[b + (((0 + r) & 3) << 2)];
            const float4 v1 = *(const float4*)&arena[b + (((1 + r) & 3) << 2)];
            const float4 v2 = *(const float4*)&arena[b + (((2 + r) & 3) << 2)];
            const float4 v3 = *(const float4*)&arena[b + (((3 + r) & 3) << 2)];
            c0.x += v0.x; c0.y += v0.y; c0.z += v0.z; c0.w += v0.w;
            c1.x += v1.x; c1.y += v1.y; c1.z += v1.z; c1.w += v1.w;
            c2.x += v2.x; c2.y += v2.y; c2.z += v2.z; c2.w += v2.w;
            c3.x += v3.x; c3.y += v3.y; c3.z += v3.z; c3.w += v3.w;
        }
        if (!half) {  // self-loop
            const int b = HS2 + i * 16;
            const int r = (i >> 1) & 3;
            const float4 v0 = *(const float4*)&arena[b + (((0 + r) & 3) << 2)];
            const float4 v1 = *(const float4*)&arena[b + (((1 + r) & 3) << 2)];
            const float4 v2 = *(const float4*)&arena[b + (((2 + r) & 3) << 2)];
            const float4 v3 = *(const float4*)&arena[b + (((3 + r) & 3) << 2)];
            c0.x += v0.x; c0.y += v0.y; c0.z += v0.z; c0.w += v0.w;
            c1.x += v1.x; c1.y += v1.y; c1.z += v1.z; c1.w += v1.w;
            c2.x += v2.x; c2.y += v2.y; c2.z += v2.z; c2.w += v2.w;
            c3.x += v3.x; c3.y += v3.y; c3.z += v3.z; c3.w += v3.w;
        }
        c0.x += __shfl_xor(c0.x, 1); c0.y += __shfl_xor(c0.y, 1);
        c0.z += __shfl_xor(c0.z, 1); c0.w += __shfl_xor(c0.w, 1);
        c1.x += __shfl_xor(c1.x, 1); c1.y += __shfl_xor(c1.y, 1);
        c1.z += __shfl_xor(c1.z, 1); c1.w += __shfl_xor(c1.w, 1);
        c2.x += __shfl_xor(c2.x, 1); c2.y += __shfl_xor(c2.y, 1);
        c2.z += __shfl_xor(c2.z, 1); c2.w += __shfl_xor(c2.w, 1);
        c3.x += __shfl_xor(c3.x, 1); c3.y += __shfl_xor(c3.y, 1);
        c3.z += __shfl_xor(c3.z, 1); c3.w += __shfl_xor(c3.w, 1);
        const float di = dinv[i];
        if (!half) {
            c0.x *= di; c0.y *= di; c0.z *= di; c0.w *= di;
            c1.x *= di; c1.y *= di; c1.z *= di; c1.w *= di;
            *(float4*)&arena[A2 + i * 16 + 0] = c0;
            *(float4*)&arena[A2 + i * 16 + 4] = c1;
        } else {
            c2.x *= di; c2.y *= di; c2.z *= di; c2.w *= di;
            c3.x *= di; c3.y *= di; c3.z *= di; c3.w *= di;
            *(float4*)&arena[A2 + i * 16 + 8]  = c2;
            *(float4*)&arena[A2 + i * 16 + 12] = c3;
        }
    }
    __syncthreads();

    // ---- layer 2 transform: h2 = relu(A2 . W2 + b2), w2 column in registers ----
    if (t < 252) {
        const int f2 = t % 28, ic = t / 28;     // 28 cols x 9 node chunks
        float wc[16];
        #pragma unroll
        for (int k = 0; k < 16; ++k) wc[k] = w2s[k * F2 + f2];
        const float bb = b2s[f2];
        for (int i = ic; i < NPG; i += 9) {
            const float4 h0 = *(const float4*)&arena[A2 + i * 16 + 0];
            const float4 h1v = *(const float4*)&arena[A2 + i * 16 + 4];
            const float4 h2v = *(const float4*)&arena[A2 + i * 16 + 8];
            const float4 h3 = *(const float4*)&arena[A2 + i * 16 + 12];
            float acc = bb;
            acc = fmaf(h0.x, wc[0], acc);  acc = fmaf(h0.y, wc[1], acc);
            acc = fmaf(h0.z, wc[2], acc);  acc = fmaf(h0.w, wc[3], acc);
            acc = fmaf(h1v.x, wc[4], acc); acc = fmaf(h1v.y, wc[5], acc);
            acc = fmaf(h1v.z, wc[6], acc); acc = fmaf(h1v.w, wc[7], acc);
            acc = fmaf(h2v.x, wc[8], acc); acc = fmaf(h2v.y, wc[9], acc);
            acc = fmaf(h2v.z, wc[10], acc); acc = fmaf(h2v.w, wc[11], acc);
            acc = fmaf(h3.x, wc[12], acc); acc = fmaf(h3.y, wc[13], acc);
            acc = fmaf(h3.z, wc[14], acc); acc = fmaf(h3.w, wc[15], acc);
            arena[H2 + i * F2 + f2] = fmaxf(acc, 0.f);
        }
    }
    __syncthreads();

    // ---- head: g = relu(h2_flat @ lw1 + lb1); out = g @ lw2 + lb2 ----
    float pj[16];
    #pragma unroll
    for (int j = 0; j < 16; ++j) pj[j] = 0.f;
    const float4* lw14 = (const float4*)lw1;
    for (int r = t; r < NPG * F2; r += 256) {
        float hv = arena[H2 + r];
        float4 a = lw14[r * 4 + 0];
        float4 b = lw14[r * 4 + 1];
        float4 c = lw14[r * 4 + 2];
        float4 d = lw14[r * 4 + 3];
        pj[0]  = fmaf(hv, a.x, pj[0]);  pj[1]  = fmaf(hv, a.y, pj[1]);
        pj[2]  = fmaf(hv, a.z, pj[2]);  pj[3]  = fmaf(hv, a.w, pj[3]);
        pj[4]  = fmaf(hv, b.x, pj[4]);  pj[5]  = fmaf(hv, b.y, pj[5]);
        pj[6]  = fmaf(hv, b.z, pj[6]);  pj[7]  = fmaf(hv, b.w, pj[7]);
        pj[8]  = fmaf(hv, c.x, pj[8]);  pj[9]  = fmaf(hv, c.y, pj[9]);
        pj[10] = fmaf(hv, c.z, pj[10]); pj[11] = fmaf(hv, c.w, pj[11]);
        pj[12] = fmaf(hv, d.x, pj[12]); pj[13] = fmaf(hv, d.y, pj[13]);
        pj[14] = fmaf(hv, d.z, pj[14]); pj[15] = fmaf(hv, d.w, pj[15]);
    }
    #pragma unroll
    for (int j = 0; j < 16; ++j) {
        float v = pj[j];
        v += __shfl_xor(v, 1);
        v += __shfl_xor(v, 2);
        v += __shfl_xor(v, 4);
        v += __shfl_xor(v, 8);
        v += __shfl_xor(v, 16);
        v += __shfl_xor(v, 32);
        pj[j] = v;
    }
    if ((t & 63) == 0) {
        int wid = t >> 6;
        #pragma unroll
        for (int j = 0; j < 16; ++j) wsum[wid * 16 + j] = pj[j];
    }
    __syncthreads();
    if (t < 16) {
        float s = wsum[t] + wsum[16 + t] + wsum[32 + t] + wsum[48 + t];
        gsh[t] = fmaxf(s + lb1s[t], 0.f);
    }
    __syncthreads();
    if (t < 2) {
        float o = lb2s[t];
        #pragma unroll
        for (int j = 0; j < 16; ++j) o = fmaf(gsh[j], lw2s[j * 2 + t], o);
        out[g * 2 + t] = o;
    }
}

extern "C" void kernel_launch(void* const* d_in, const int* in_sizes, int n_in,
                              void* d_out, int out_size, void* d_ws, size_t ws_size,
                              hipStream_t stream) {
    const float* x   = (const float*)d_in[0];
    const int*   ei  = (const int*)d_in[1];
    const float* W1  = (const float*)d_in[2];
    const float* b1  = (const float*)d_in[3];
    const float* W2  = (const float*)d_in[4];
    const float* b2  = (const float*)d_in[5];
    const float* lw1 = (const float*)d_in[6];
    const float* lb1 = (const float*)d_in[7];
    const float* lw2 = (const float*)d_in[8];
    const float* lb2 = (const float*)d_in[9];
    float* out = (float*)d_out;

    gcn_fused<<<NGRAPH, 256, 0, stream>>>(x, ei, W1, b1, W2, b2,
                                          lw1, lb1, lw2, lb2, out);
}